// Round 7
// baseline (13271.014 us; speedup 1.0000x reference)
//
#include <hip/hip_runtime.h>
#include <math.h>

// ESN recurrence: x_t = tanh(u_t @ w_in^T + w_bias + W @ h_{t-1}), h_0 = 0.
// B=8, T=4096, D_RES=1024, D_IN=64, fp32.
//
// R9: R8 (A/B batch pairing) REVERTED — measured 9044us vs R5's 6245us:
// FETCH 160->283MB (2x consumers/batch) and VALUBusy 28->19% show the A/B
// phases serialized into a 64-WG-fanout lockstep chain instead of hiding
// latency. Back to R5's structure; this round removes R5's intra-WG
// serialization instead:
//
//  1) BARRIER-FREE LDS DATAFLOW: stagers write the tagged u64 (tag|bits)
//     into LDS; consumers validate per-element tags from LDS and spin
//     locally (~120cy LDS RT vs 600cy IC RT). No __syncthreads in the loop.
//  2) DUAL-SET IC SAMPLING: two 4-load sample sets kept in flight,
//     alternating issue/check -> detect quantization ~RT/2 instead of RT.
//  3) GROUP-PIPELINED CONSUME: 4 groups x 8 ds_read_b64, prefetched one
//     group ahead; FMAs overlap the next group's reads. j-order stays
//     0..31 ascending -> bit-identical numerics (absmax 0.00390625).
//
// Safety of barrier removal (max-skew induction): a wave's consume at step
// s reads ALL 1024 LDS cells (each lane reads its full mod-32 residue
// class), each requiring tag >= s, which requires every stager of its WG
// passed IC-spin(s), which requires x_{s-1} globally complete, which
// requires EVERY wave everywhere completed step s-1 (publish is the last
// act of a step). Hence: any wave at step s implies all waves finished
// s-1 -> max skew is 1 step. Therefore (a) a stager writing lds[p] at
// step t (t even, say) implies all waves finished t-1, so no reader of
// lds[p] from step t-2 remains; (b) a publisher overwriting IC slot
// (t-1)&1 with x_{t+1} implies all waves finished step t, so no IC-spinner
// for x_{t-1} remains. Both 2-deep buffers stay safe without barriers.
// Waves are SIMT-lockstep internally, so per-wave full coverage is the
// gating unit. Tags monotonic; hbuf + LDS tags zeroed before the loop.

#define NB        8
#define T_STEPS   4096
#define DRES      1024
#define DIN       64
#define NTHREADS  256

typedef unsigned long long u64;

#define HBUF_BYTES (2 * NB * DRES * sizeof(u64))   // 128 KB, zeroed per launch

// Butterfly sum over 32 lanes, bit-identical to the 5-round __shfl_xor tree.
__device__ __forceinline__ float bfly32(float v) {
    v += __int_as_float(__builtin_amdgcn_update_dpp(
            0, __float_as_int(v), 0xB1, 0xF, 0xF, true));   // xor1 (quad_perm)
    v += __int_as_float(__builtin_amdgcn_update_dpp(
            0, __float_as_int(v), 0x4E, 0xF, 0xF, true));   // xor2 (quad_perm)
    v += __int_as_float(__builtin_amdgcn_update_dpp(
            0, __float_as_int(v), 0x141, 0xF, 0xF, true));  // xor4 via half_mirror
    v += __int_as_float(__builtin_amdgcn_update_dpp(
            0, __float_as_int(v), 0x140, 0xF, 0xF, true));  // xor8 via mirror
    v += __int_as_float(__builtin_amdgcn_ds_swizzle(
            __float_as_int(v), 0x401F));                    // xor16
    return v;
}

__device__ __forceinline__ void ic_load4(u64 (&s)[4], const u64* hs, int tid) {
    #pragma unroll
    for (int i = 0; i < 4; ++i) {
        s[i] = __hip_atomic_load(hs + tid + 256 * i,
                                 __ATOMIC_RELAXED, __HIP_MEMORY_SCOPE_AGENT);
    }
}

__device__ __forceinline__ unsigned min4(const u64 (&s)[4]) {
    unsigned mn = 0xFFFFFFFFu;
    #pragma unroll
    for (int i = 0; i < 4; ++i) {
        const unsigned tg = (unsigned)(s[i] >> 32);
        mn = tg < mn ? tg : mn;
    }
    return mn;
}

__device__ __forceinline__ void lds_load8(u64 (&d)[8], const u64* lp, int base) {
    #pragma unroll
    for (int k = 0; k < 8; ++k) {
        d[k] = __hip_atomic_load(lp + base + 32 * k,
                                 __ATOMIC_RELAXED, __HIP_MEMORY_SCOPE_WORKGROUP);
    }
}

__device__ __forceinline__ unsigned min8(const u64 (&d)[8]) {
    unsigned mn = 0xFFFFFFFFu;
    #pragma unroll
    for (int k = 0; k < 8; ++k) {
        const unsigned tg = (unsigned)(d[k] >> 32);
        mn = tg < mn ? tg : mn;
    }
    return mn;
}

__device__ __forceinline__ void lds_spin8(u64 (&d)[8], const u64* lp, int base,
                                          unsigned tgt) {
    int tries = 0;
    while (min8(d) < tgt) {                      // rare: stagers slightly behind
        if (((++tries) & 15) == 0) __builtin_amdgcn_s_sleep(1);
        lds_load8(d, lp, base);
    }
}

__device__ __forceinline__ void fma8(float (&acc)[4], const u64 (&d)[8],
                                     const float (&wreg)[4][32], int jbase) {
    #pragma unroll
    for (int k = 0; k < 8; ++k) {
        const float hv = __uint_as_float((unsigned)d[k]);
        #pragma unroll
        for (int i = 0; i < 4; ++i) {
            acc[i] = fmaf(wreg[i][jbase + k], hv, acc[i]);
        }
    }
}

__launch_bounds__(NTHREADS, 1)
__global__ void esn_kernel(const float* __restrict__ u,      // [NB][T][DIN]
                           const float* __restrict__ w_in,   // [DRES][DIN]
                           const float* __restrict__ w,      // [DRES][DRES]
                           const float* __restrict__ w_bias, // [DRES]
                           float* __restrict__ out,          // [NB][T][DRES]
                           u64* __restrict__ hbuf)           // [2][NB][DRES] (tag|bits)
{
    const int tid   = threadIdx.x;
    const int b     = (int)blockIdx.x & (NB - 1);   // batch -> XCD affinity heuristic
    const int chunk = (int)blockIdx.x >> 3;         // 0..31 row-chunk
    const int rg    = tid >> 5;                     // 0..7 row-group (4 rows each)
    const int mc    = tid & 31;                     // 0..31 k-lane
    const int row0  = chunk * 32 + rg * 4;          // first of this thread's 4 rows

    __shared__ u64 lds_h[2][DRES];                  // tagged h stage, 2-deep (16 KB)

    // ---- prologue: weights into registers ----
    float wreg[4][32];                              // wreg[i][j] = W[row0+i][mc+32j]
    #pragma unroll
    for (int i = 0; i < 4; ++i) {
        const float* wr = w + (size_t)(row0 + i) * DRES + mc;
        #pragma unroll
        for (int j = 0; j < 32; ++j) {
            wreg[i][j] = wr[32 * j];
        }
    }
    float win0[4], win1[4], bias[4];
    #pragma unroll
    for (int i = 0; i < 4; ++i) {
        win0[i] = w_in[(row0 + i) * DIN + 2 * mc];
        win1[i] = w_in[(row0 + i) * DIN + 2 * mc + 1];
        bias[i] = w_bias[row0 + i];
    }

    // zero LDS tags (both parities); the only barrier in the kernel
    #pragma unroll
    for (int k = 0; k < 8; ++k) {
        ((u64*)lds_h)[tid + 256 * k] = 0ull;
    }
    __syncthreads();

    const float* ub = u + (size_t)b * T_STEPS * DIN;
    u64* const hb0 = hbuf + (size_t)b * DRES;            // slot for even t
    u64* const hb1 = hbuf + (size_t)(NB + b) * DRES;     // slot for odd t

    float2 ucur = *(const float2*)(ub + 2 * mc);

    // ---- t = 0 peeled: h_0 = 0, recurrent term vanishes ----
    {
        const float2 unext = *(const float2*)(ub + DIN + 2 * mc);
        float acc[4];
        #pragma unroll
        for (int i = 0; i < 4; ++i) {
            acc[i] = fmaf(win0[i], ucur.x, win1[i] * ucur.y);
        }
        #pragma unroll
        for (int i = 0; i < 4; ++i) {
            acc[i] = bfly32(acc[i]);
        }
        float x[4];
        #pragma unroll
        for (int i = 0; i < 4; ++i) {
            const float z = acc[i] + bias[i];
            const float e = __expf(2.0f * z);
            x[i] = 1.0f - 2.0f / (e + 1.0f);
        }
        if (mc < 4) {
            const float v = (mc & 2) ? ((mc & 1) ? x[3] : x[2])
                                     : ((mc & 1) ? x[1] : x[0]);
            __hip_atomic_store(hb0 + row0 + mc,
                               ((u64)1u << 32) | (u64)__float_as_uint(v),
                               __ATOMIC_RELAXED, __HIP_MEMORY_SCOPE_AGENT);
        }
        if (mc == 0) {
            *(float4*)(out + (size_t)b * T_STEPS * DRES + row0) =
                make_float4(x[0], x[1], x[2], x[3]);
        }
        ucur = unext;
    }

    #pragma unroll 1
    for (int t = 1; t < T_STEPS; ++t) {
        u64* const hs = (t & 1) ? hb0 : hb1;      // IC slot holding x_{t-1} (tag t)
        u64* const hp = (t & 1) ? hb1 : hb0;      // IC slot for x_t (tag t+1)
        const u64* lp = &lds_h[t & 1][0];         // LDS stage for this step
        u64* lq       = &lds_h[t & 1][0];
        const unsigned tgt = (unsigned)t;
        const int tn = (t + 1 < T_STEPS) ? (t + 1) : t;

        // u prefetch flies under the whole step
        const float2 unext = *(const float2*)(ub + (size_t)tn * DIN + 2 * mc);

        // ---- stager role: own 4 tagged elements, dual-set IC sampling ----
        u64 sA[4];
        ic_load4(sA, hs, tid);
        if (min4(sA) < tgt) {
            u64 sB[4];
            ic_load4(sB, hs, tid);
            int tries = 0;
            for (;;) {
                if (min4(sA) >= tgt) break;
                ic_load4(sA, hs, tid);
                if (min4(sB) >= tgt) {
                    #pragma unroll
                    for (int i = 0; i < 4; ++i) sA[i] = sB[i];
                    break;
                }
                ic_load4(sB, hs, tid);
                if (((++tries) & 15) == 0) __builtin_amdgcn_s_sleep(1);
            }
        }
        #pragma unroll
        for (int i = 0; i < 4; ++i) {
            __hip_atomic_store(lq + tid + 256 * i, sA[i],
                               __ATOMIC_RELAXED, __HIP_MEMORY_SCOPE_WORKGROUP);
        }

        // input projection (VALU, overlaps neighbors' staging)
        float acc[4];
        #pragma unroll
        for (int i = 0; i < 4; ++i) {
            acc[i] = fmaf(win0[i], ucur.x, win1[i] * ucur.y);
        }

        // ---- consumer role: 4 groups x 8 elements, prefetched pipeline ----
        // j-order 0..31 ascending -> FMA order identical to R5.
        u64 ga[8], gb[8];
        lds_load8(ga, lp, mc);                    // group 0 (j=0..7)
        lds_load8(gb, lp, mc + 256);              // group 1 prefetch
        lds_spin8(ga, lp, mc, tgt);       fma8(acc, ga, wreg, 0);
        lds_load8(ga, lp, mc + 512);              // group 2 prefetch
        lds_spin8(gb, lp, mc + 256, tgt); fma8(acc, gb, wreg, 8);
        lds_load8(gb, lp, mc + 768);              // group 3 prefetch
        lds_spin8(ga, lp, mc + 512, tgt); fma8(acc, ga, wreg, 16);
        lds_spin8(gb, lp, mc + 768, tgt); fma8(acc, gb, wreg, 24);

        // butterfly reduce (DPP + 1 ds_swizzle; bit-identical tree)
        #pragma unroll
        for (int i = 0; i < 4; ++i) {
            acc[i] = bfly32(acc[i]);
        }

        float x[4];
        #pragma unroll
        for (int i = 0; i < 4; ++i) {
            const float z = acc[i] + bias[i];
            const float e = __expf(2.0f * z);
            x[i] = 1.0f - 2.0f / (e + 1.0f);
        }

        // publish tagged h first (latency-critical path to consumers)
        if (t + 1 < T_STEPS && mc < 4) {
            const float v = (mc & 2) ? ((mc & 1) ? x[3] : x[2])
                                     : ((mc & 1) ? x[1] : x[0]);
            __hip_atomic_store(hp + row0 + mc,
                               ((u64)(unsigned)(t + 1) << 32) |
                               (u64)__float_as_uint(v),
                               __ATOMIC_RELAXED, __HIP_MEMORY_SCOPE_AGENT);
        }
        // output store: normal cached path (nobody reads it; L2 writes back lazily)
        if (mc == 0) {
            *(float4*)(out + ((size_t)b * T_STEPS + t) * DRES + row0) =
                make_float4(x[0], x[1], x[2], x[3]);
        }

        ucur = unext;
    }
}

extern "C" void kernel_launch(void* const* d_in, const int* in_sizes, int n_in,
                              void* d_out, int out_size, void* d_ws, size_t ws_size,
                              hipStream_t stream) {
    const float* u      = (const float*)d_in[0];
    const float* w_in   = (const float*)d_in[1];
    const float* w      = (const float*)d_in[2];
    const float* w_bias = (const float*)d_in[3];
    float* out = (float*)d_out;
    u64* hbuf = (u64*)d_ws;

    // tags must start below 1 (ws is re-poisoned before every call)
    hipMemsetAsync(hbuf, 0, HBUF_BYTES, stream);

    esn_kernel<<<NB * 32, NTHREADS, 0, stream>>>(u, w_in, w, w_bias, out, hbuf);
}